// Round 4
// baseline (495.431 us; speedup 1.0000x reference)
//
#include <hip/hip_runtime.h>

// ---------------------------------------------------------------------------
// Attention_17703855194398: AdaRMSNorm -> QKV -> per-head RMS+RoPE -> SDPA -> out
// B=2, L=2048, D=2048, NH=32, HD=64, DC=2048
// R4: rope fused into QKV-GEMM epilogue (fp32), V stores packed dwordx2,
//     attn single-barrier pipelined K/V staging (LDS double-buffer).
// ---------------------------------------------------------------------------

typedef __bf16 bf16x8 __attribute__((ext_vector_type(8)));
typedef float  f32x4  __attribute__((ext_vector_type(4)));
typedef float  f32x16 __attribute__((ext_vector_type(16)));

#define EPS_F32 1.1920929e-07f
// q prescale: (1/sqrt(64)) * log2(e)  -> scores land in exp2 domain
#define QSCALE 0.18033688011112042f

#if defined(__has_builtin)
#  if __has_builtin(__builtin_amdgcn_exp2f)
#    define EXP2F(x) __builtin_amdgcn_exp2f(x)
#  else
#    define EXP2F(x) __expf((x) * 0.6931471805599453f)
#  endif
#  if __has_builtin(__builtin_amdgcn_rcpf)
#    define RCPF(x) __builtin_amdgcn_rcpf(x)
#  else
#    define RCPF(x) (1.0f / (x))
#  endif
#else
#  define EXP2F(x) __expf((x) * 0.6931471805599453f)
#  define RCPF(x) (1.0f / (x))
#endif

__device__ __forceinline__ float bf2f(unsigned int u16) {
  union { unsigned int i; float f; } v; v.i = (u16 & 0xffffu) << 16; return v.f;
}
__device__ __forceinline__ unsigned short f2bf(float f) {
  union { float f; unsigned int i; } v; v.f = f;
  unsigned int r = v.i + 0x7fffu + ((v.i >> 16) & 1u);  // RNE
  return (unsigned short)(r >> 16);
}
// round-to-nearest (ties away) bf16 bits, cheap
__device__ __forceinline__ unsigned int f2bf_rn_u(float f) {
  union { float f; unsigned int i; } v; v.f = f;
  return v.i + 0x8000u;   // caller takes >>16 or &0xffff0000
}

// async global->LDS, 16B per lane (wave-uniform base + lane*16)
__device__ __forceinline__ void gload16(const void* g, void* l) {
  __builtin_amdgcn_global_load_lds(
      (const __attribute__((address_space(1))) unsigned int*)(unsigned long long)g,
      (__attribute__((address_space(3))) unsigned int*)(unsigned int)(unsigned long long)l,
      16, 0, 0);
}

// ---------------------------------------------------------------------------
// 1) ada GEMM: ss[b,j] = sum_k cond[b,k] * w_ada[j,k]
// ---------------------------------------------------------------------------
__global__ __launch_bounds__(256) void ada_gemm_kernel(
    const float* __restrict__ cond, const float* __restrict__ w_ada,
    float* __restrict__ ss)
{
  const int lane = threadIdx.x & 63;
  const int gw = blockIdx.x * 4 + (threadIdx.x >> 6);
  const int b = gw >> 12;
  const int j = gw & 4095;
  const float4* wr = (const float4*)(w_ada + j * 2048);
  const float4* cr = (const float4*)(cond + b * 2048);
  float acc = 0.f;
  #pragma unroll
  for (int k4 = 0; k4 < 8; ++k4) {
    float4 w = wr[lane + k4 * 64];
    float4 c = cr[lane + k4 * 64];
    acc += w.x * c.x + w.y * c.y + w.z * c.z + w.w * c.w;
  }
  #pragma unroll
  for (int off = 1; off < 64; off <<= 1) acc += __shfl_xor(acc, off);
  if (lane == 0) ss[b * 4096 + j] = acc;
}

// ---------------------------------------------------------------------------
// 2) AdaRMSNorm: h = rms_norm(x)*(1+scale) + shift, write bf16
// ---------------------------------------------------------------------------
__global__ __launch_bounds__(256) void ada_rms_kernel(
    const float* __restrict__ x, const float* __restrict__ ss,
    unsigned short* __restrict__ H)
{
  const int row = blockIdx.x;
  const int b = row >> 11;
  const int tid = threadIdx.x;
  const int lane = tid & 63, wave = tid >> 6;
  const float* xr = x + (size_t)row * 2048;
  float4 v0 = ((const float4*)xr)[tid * 2];
  float4 v1 = ((const float4*)xr)[tid * 2 + 1];
  float ssq = v0.x*v0.x + v0.y*v0.y + v0.z*v0.z + v0.w*v0.w
            + v1.x*v1.x + v1.y*v1.y + v1.z*v1.z + v1.w*v1.w;
  #pragma unroll
  for (int off = 1; off < 64; off <<= 1) ssq += __shfl_xor(ssq, off);
  __shared__ float red[4];
  if (lane == 0) red[wave] = ssq;
  __syncthreads();
  const float tot = red[0] + red[1] + red[2] + red[3];
  const float r = rsqrtf(tot * (1.f / 2048.f) + EPS_F32);
  const int c0 = tid * 8;
  const float* sh = ss + b * 4096;
  float xv[8] = {v0.x, v0.y, v0.z, v0.w, v1.x, v1.y, v1.z, v1.w};
  unsigned int pk[4];
  #pragma unroll
  for (int p = 0; p < 4; ++p) {
    const int c = c0 + p * 2;
    float h0 = xv[p*2+0] * r * (1.f + sh[2048 + c])     + sh[c];
    float h1 = xv[p*2+1] * r * (1.f + sh[2048 + c + 1]) + sh[c + 1];
    pk[p] = (unsigned int)f2bf(h0) | ((unsigned int)f2bf(h1) << 16);
  }
  *(uint4*)&H[(size_t)row * 2048 + c0] = make_uint4(pk[0], pk[1], pk[2], pk[3]);
}

// ---------------------------------------------------------------------------
// 3) weight cast (fp32->bf16) + rope float2 repack, one launch.
//    blocks < 16384: weights; blocks >= 16384: rope2[l*64+d] = {r0, r1}
// ---------------------------------------------------------------------------
__global__ __launch_bounds__(256) void cast2_kernel(
    const float* __restrict__ a,   // w_qkv, 3145728 float4
    const float* __restrict__ b,   // w_out, 1048576 float4
    const float* __restrict__ rope,
    unsigned short* __restrict__ dst,
    float2* __restrict__ rope2)
{
  const int blk = blockIdx.x;
  if (blk < 16384) {
    const int i = blk * 256 + threadIdx.x;
    float4 v = (i < 3145728) ? ((const float4*)a)[i]
                             : ((const float4*)b)[i - 3145728];
    unsigned int p0 = (unsigned int)f2bf(v.x) | ((unsigned int)f2bf(v.y) << 16);
    unsigned int p1 = (unsigned int)f2bf(v.z) | ((unsigned int)f2bf(v.w) << 16);
    *(uint2*)&dst[(size_t)i * 4] = make_uint2(p0, p1);
  } else {
    const int i2 = (blk - 16384) * 256 + threadIdx.x;   // 0..131071
    rope2[i2] = make_float2(rope[i2], rope[131072 + i2]);
  }
}

// ---------------------------------------------------------------------------
// 4) bf16 MFMA GEMM, C[M,N] = A[M,K] @ Bw[N,K]^T (m97 structure).
//    MODE 0: f32 C.
//    MODE 2 (QKV): bn<4096 -> per-head RMS + RoPE (+QSCALE for q) fused on the
//    fp32 accumulator, bf16 C. bn>=4096 (V third) -> Vt[bh][d][k-perm], 4
//    perm-contiguous i-values packed per dwordx2 store.
// ---------------------------------------------------------------------------
template <int MODE>
__global__ __launch_bounds__(256) void gemm_bt_kernel(
    const unsigned short* __restrict__ A,   // [M,K] bf16
    const unsigned short* __restrict__ Bw,  // [N,K] bf16
    void* __restrict__ Cv,                  // [M,N] bf16 or f32
    unsigned short* __restrict__ vt,        // MODE 2 only
    const float* __restrict__ qk_w,         // MODE 2 only
    const float2* __restrict__ rope2,       // MODE 2 only
    int M, int N, int K)
{
  __shared__ unsigned short As[128 * 32];
  __shared__ unsigned short Bs[128 * 32];
  const int tid  = threadIdx.x;
  const int lane = tid & 63;
  const int wave = tid >> 6;
  const int wm = (wave >> 1) * 64;
  const int wn = (wave & 1) * 64;
  const int bm = blockIdx.y * 128;
  const int bn = blockIdx.x * 128;

  f32x4 acc[4][4] = {};

  const int sm = tid >> 2;
  const int sk = (tid & 3) * 8;
  const unsigned short* Ap  = A  + (size_t)(bm + sm) * K + sk;
  const unsigned short* Ap2 = Ap + (size_t)64 * K;
  const unsigned short* Bp  = Bw + (size_t)(bn + sm) * K + sk;
  const unsigned short* Bp2 = Bp + (size_t)64 * K;
  unsigned short* lA  = &As[tid * 8];
  unsigned short* lA2 = &As[tid * 8 + 2048];
  unsigned short* lB  = &Bs[tid * 8];
  unsigned short* lB2 = &Bs[tid * 8 + 2048];

  const int fr = lane & 15;
  const int fk = (lane >> 4) * 8;

  for (int k0 = 0; k0 < K; k0 += 32) {
    __syncthreads();
    gload16(Ap  + k0, lA);
    gload16(Ap2 + k0, lA2);
    gload16(Bp  + k0, lB);
    gload16(Bp2 + k0, lB2);
    __syncthreads();

    bf16x8 af[4], bfr[4];
    #pragma unroll
    for (int i = 0; i < 4; ++i)
      af[i] = *(const bf16x8*)&As[(wm + i * 16 + fr) * 32 + fk];
    #pragma unroll
    for (int j = 0; j < 4; ++j)
      bfr[j] = *(const bf16x8*)&Bs[(wn + j * 16 + fr) * 32 + fk];
    #pragma unroll
    for (int i = 0; i < 4; ++i)
      #pragma unroll
      for (int j = 0; j < 4; ++j)
        acc[i][j] = __builtin_amdgcn_mfma_f32_16x16x32_bf16(af[i], bfr[j], acc[i][j], 0, 0, 0);
  }

  const int quad = lane >> 4;
  const int cc   = lane & 15;
  const int cr   = quad * 4;

  if (MODE == 2 && bn >= 4096) {
    // V third: Vt[((b*32+head)*64+dim)][2048 k-perm]. For fixed (lane,j,r) the
    // 4 i-values are contiguous in perm order -> one dwordx2 store.
    const int b2 = bm >> 11;
    const int lb = (bm & 2047) + wm;       // perm chunk base (wm in {0,64})
    #pragma unroll
    for (int j = 0; j < 4; ++j) {
      const int dg = bn + wn + j * 16 + cc - 4096;
      unsigned short* vrow = vt + ((size_t)((b2 * 32 + (dg >> 6)) * 64) + (dg & 63)) * 2048;
      #pragma unroll
      for (int r = 0; r < 4; ++r) {
        unsigned int u0 = (unsigned int)f2bf(acc[0][j][r]) | ((unsigned int)f2bf(acc[1][j][r]) << 16);
        unsigned int u1 = (unsigned int)f2bf(acc[2][j][r]) | ((unsigned int)f2bf(acc[3][j][r]) << 16);
        *(uint2*)&vrow[lb + (cr + r) * 4] = make_uint2(u0, u1);
      }
    }
  } else if (MODE == 2) {
    // q/k: per-head RMS (sum over the wave's 64 cols) + qk_w + RoPE on fp32 acc.
    const bool isq = (bn < 2048);
    float qkw4[4];
    #pragma unroll
    for (int j = 0; j < 4; ++j)
      qkw4[j] = qk_w[j * 16 + cc] * (isq ? QSCALE : 1.0f);
    unsigned short* C = (unsigned short*)Cv;
    #pragma unroll
    for (int i = 0; i < 4; ++i) {
      #pragma unroll
      for (int r = 0; r < 4; ++r) {
        float s2 = acc[0 + 0][0][0] * 0.f;  // keep compiler happy on init
        s2 = acc[i][0][r] * acc[i][0][r] + acc[i][1][r] * acc[i][1][r]
           + acc[i][2][r] * acc[i][2][r] + acc[i][3][r] * acc[i][3][r];
        s2 += __shfl_xor(s2, 1);
        s2 += __shfl_xor(s2, 2);
        s2 += __shfl_xor(s2, 4);
        s2 += __shfl_xor(s2, 8);
        const float irms = rsqrtf(s2 * (1.f / 64.f) + EPS_F32);
        const int m = bm + wm + i * 16 + cr + r;
        const int l = m & 2047;
        const float2* rp = rope2 + (size_t)l * 64;
        #pragma unroll
        for (int j = 0; j < 4; ++j) {
          const float vn = acc[i][j][r] * irms * qkw4[j];
          const float vp = __shfl_xor(vn, 1);
          const float vh = (cc & 1) ? vp : -vp;
          const float2 rr = rp[j * 16 + cc];
          C[(size_t)m * N + bn + wn + j * 16 + cc] = f2bf(vn * rr.x + vh * rr.y);
        }
      }
    }
  } else {
    float* C = (float*)Cv;
    #pragma unroll
    for (int i = 0; i < 4; ++i)
      #pragma unroll
      for (int j = 0; j < 4; ++j)
        #pragma unroll
        for (int r = 0; r < 4; ++r)
          C[(size_t)(bm + wm + i * 16 + cr + r) * N + bn + wn + j * 16 + cc] = acc[i][j][r];
  }
}

// ---------------------------------------------------------------------------
// 5) MFMA flash attention (no-max softmax). 64q/wave, 256q/block, k-tile 64.
//    Pipelined: LDS K/V double-buffer, ONE barrier per kt; next-tile global
//    loads issued before compute, consumed by ds_write after compute (latency
//    hidden inside the iteration, no vmcnt(0)-at-barrier exposure).
// ---------------------------------------------------------------------------
#define KVSZ (64 * 72)
__global__ __launch_bounds__(256, 2) void attn_mfma_kernel(
    const unsigned short* __restrict__ QKV,  // [4096][6144] (q,k roped)
    const unsigned short* __restrict__ Vt,   // [64 bh][64 d][2048 k-perm]
    unsigned short* __restrict__ O)          // [4096][2048]
{
  __shared__ unsigned short Kb[2 * KVSZ];
  __shared__ unsigned short Vb[2 * KVSZ];
  __shared__ unsigned short Ps[4 * 64 * 68];
  const int tid  = threadIdx.x;
  const int lane = tid & 63;
  const int wave = tid >> 6;
  const int blk = blockIdx.x;              // 0..511
  const int bh = blk & 63;                 // XCD-affine
  const int qt = blk >> 6;                 // 0..7
  const int b = bh >> 5, h = bh & 31;
  const int rowbase = b << 11;
  const int qbase = qt * 256 + wave * 64;

  const int m16  = lane & 15;
  const int quad = lane >> 4;
  const int m32  = lane & 31;
  const int hl   = lane >> 5;

  // Q fragments (QSCALE already folded in by the fused GEMM epilogue)
  bf16x8 qf[4][2];
  #pragma unroll
  for (int qi = 0; qi < 4; ++qi)
    #pragma unroll
    for (int ch = 0; ch < 2; ++ch)
      qf[qi][ch] = *(const bf16x8*)&QKV[(size_t)(rowbase + qbase + qi * 16 + m16) * 6144
                                        + h * 64 + ch * 32 + quad * 8];

  const int sr = tid >> 2;            // staging row 0..63
  const int sc = (tid & 3) * 16;      // staging col (shorts)
  const unsigned short* Kg = QKV + (size_t)(rowbase + sr) * 6144 + 2048 + h * 64 + sc;
  const unsigned short* Vg = Vt + (size_t)(bh * 64 + sr) * 2048 + sc;

  f32x16 accO[2][2] = {};
  float part[4][4] = {};
  unsigned short* Pw = &Ps[(wave * 64) * 68];

  // stage kt=0
  {
    const uint4* kp = (const uint4*)Kg;
    const uint4* vp = (const uint4*)Vg;
    uint4 k0 = kp[0], k1 = kp[1], v0 = vp[0], v1 = vp[1];
    *(uint4*)&Kb[sr * 72 + sc]     = k0;
    *(uint4*)&Kb[sr * 72 + sc + 8] = k1;
    *(uint4*)&Vb[sr * 72 + sc]     = v0;
    *(uint4*)&Vb[sr * 72 + sc + 8] = v1;
  }
  __syncthreads();

  for (int kt = 0; kt < 32; ++kt) {
    const int cur = kt & 1;
    // issue next-tile loads now; consumed after compute
    uint4 ka, kb2, va, vb2;
    if (kt < 31) {
      const uint4* kp = (const uint4*)(Kg + (size_t)(kt + 1) * 64 * 6144);
      const uint4* vp = (const uint4*)(Vg + (kt + 1) * 64);
      ka = kp[0]; kb2 = kp[1]; va = vp[0]; vb2 = vp[1];
    }
    const unsigned short* Ksc = &Kb[cur * KVSZ];
    const unsigned short* Vsc = &Vb[cur * KVSZ];

    // S (16x16x32) -> exp2 -> pack P (key perm p = c*4 + kj)
    unsigned int pk[4][4][2];
    #pragma unroll
    for (int kj = 0; kj < 4; ++kj) {
      bf16x8 kf0 = *(const bf16x8*)&Ksc[(kj * 16 + m16) * 72 + quad * 8];
      bf16x8 kf1 = *(const bf16x8*)&Ksc[(kj * 16 + m16) * 72 + 32 + quad * 8];
      #pragma unroll
      for (int qi = 0; qi < 4; ++qi) {
        f32x4 acc = {};
        acc = __builtin_amdgcn_mfma_f32_16x16x32_bf16(qf[qi][0], kf0, acc, 0, 0, 0);
        acc = __builtin_amdgcn_mfma_f32_16x16x32_bf16(qf[qi][1], kf1, acc, 0, 0, 0);
        #pragma unroll
        for (int r = 0; r < 4; ++r) {
          float p = EXP2F(acc[r]);
          part[qi][r] += p;
          unsigned int pb = f2bf_rn_u(p);
          if (kj == 0)      pk[qi][r][0]  = pb >> 16;
          else if (kj == 1) pk[qi][r][0] |= pb & 0xffff0000u;
          else if (kj == 2) pk[qi][r][1]  = pb >> 16;
          else              pk[qi][r][1] |= pb & 0xffff0000u;
        }
      }
    }
    #pragma unroll
    for (int qi = 0; qi < 4; ++qi)
      #pragma unroll
      for (int r = 0; r < 4; ++r)
        *(uint2*)&Pw[(qi * 16 + quad * 4 + r) * 68 + m16 * 4] =
            make_uint2(pk[qi][r][0], pk[qi][r][1]);
    // wave-private P region: RAW covered by lgkmcnt, no barrier

    // PV (32x32x16): accO[qs][dt]
    #pragma unroll
    for (int ch = 0; ch < 4; ++ch) {
      bf16x8 pa0 = *(const bf16x8*)&Pw[m32 * 68 + ch * 16 + hl * 8];
      bf16x8 pa1 = *(const bf16x8*)&Pw[(32 + m32) * 68 + ch * 16 + hl * 8];
      bf16x8 vb0 = *(const bf16x8*)&Vsc[m32 * 72 + ch * 16 + hl * 8];
      bf16x8 vb1 = *(const bf16x8*)&Vsc[(32 + m32) * 72 + ch * 16 + hl * 8];
      accO[0][0] = __builtin_amdgcn_mfma_f32_32x32x16_bf16(pa0, vb0, accO[0][0], 0, 0, 0);
      accO[0][1] = __builtin_amdgcn_mfma_f32_32x32x16_bf16(pa0, vb1, accO[0][1], 0, 0, 0);
      accO[1][0] = __builtin_amdgcn_mfma_f32_32x32x16_bf16(pa1, vb0, accO[1][0], 0, 0, 0);
      accO[1][1] = __builtin_amdgcn_mfma_f32_32x32x16_bf16(pa1, vb1, accO[1][1], 0, 0, 0);
    }

    // write next tile into the other LDS buffer (disjoint from Ksc/Vsc)
    if (kt < 31) {
      unsigned short* Ksn = &Kb[(1 - cur) * KVSZ];
      unsigned short* Vsn = &Vb[(1 - cur) * KVSZ];
      *(uint4*)&Ksn[sr * 72 + sc]     = ka;
      *(uint4*)&Ksn[sr * 72 + sc + 8] = kb2;
      *(uint4*)&Vsn[sr * 72 + sc]     = va;
      *(uint4*)&Vsn[sr * 72 + sc + 8] = vb2;
    }
    __syncthreads();
  }

  // reduce row sums over the 16 n-lanes
  #pragma unroll
  for (int qi = 0; qi < 4; ++qi)
    #pragma unroll
    for (int r = 0; r < 4; ++r)
      #pragma unroll
      for (int off = 1; off < 16; off <<= 1)
        part[qi][r] += __shfl_xor(part[qi][r], off);

  // epilogue: per 32-row q-subtile, gather row sum, divide, store
  #pragma unroll
  for (int qs = 0; qs < 2; ++qs) {
    #pragma unroll
    for (int reg = 0; reg < 16; ++reg) {
      const int r = reg & 3;
      const int s = reg >> 2;
      const int qsrc = ((2 * s + hl) & 3) * 16 + m16;
      const float rs = __shfl(part[qs * 2 + (reg >> 3)][r], qsrc);
      const float inv = RCPF(rs);
      const int rho = r + 8 * s + 4 * hl;
      const size_t base = (size_t)(rowbase + qbase + qs * 32 + rho) * 2048 + h * 64;
      O[base + m32]      = f2bf(accO[qs][0][reg] * inv);
      O[base + 32 + m32] = f2bf(accO[qs][1][reg] * inv);
    }
  }
}

// ---------------------------------------------------------------------------
// launch
// ---------------------------------------------------------------------------
extern "C" void kernel_launch(void* const* d_in, const int* in_sizes, int n_in,
                              void* d_out, int out_size, void* d_ws, size_t ws_size,
                              hipStream_t stream) {
  (void)in_sizes; (void)n_in; (void)out_size; (void)ws_size;
  const float* x     = (const float*)d_in[0];
  const float* cond  = (const float*)d_in[1];
  const float* rope  = (const float*)d_in[2];
  const float* w_ada = (const float*)d_in[3];
  const float* w_qkv = (const float*)d_in[4];
  const float* w_out = (const float*)d_in[5];
  const float* qk_w  = (const float*)d_in[6];
  float* out = (float*)d_out;

  char* ws = (char*)d_ws;
  float*          ss   = (float*)ws;                       // 32 KB
  unsigned short* H    = (unsigned short*)(ws + 32768);    // 16 MB, reused as O
  unsigned short* Wq   = H + 8388608;                      // 24 MB
  unsigned short* Wo   = Wq + 12582912;                    // 8 MB (contiguous after Wq)
  unsigned short* QKV  = Wo + 4194304;                     // 48 MB (q,k used)
  unsigned short* Vt_g = QKV + 25165824;                   // 16 MB
  float2*         rope2 = (float2*)(Vt_g + 8388608);       // 1 MB

  ada_gemm_kernel<<<2048, 256, 0, stream>>>(cond, w_ada, ss);
  ada_rms_kernel<<<4096, 256, 0, stream>>>(x, ss, H);
  cast2_kernel<<<16896, 256, 0, stream>>>(w_qkv, w_out, rope, Wq, rope2);
  // qkv = H @ w_qkv^T ; q,k roped in-epilogue -> QKV, v -> Vt_g (perm)
  gemm_bt_kernel<2><<<dim3(48, 32), 256, 0, stream>>>(
      H, Wq, (void*)QKV, Vt_g, qk_w, rope2, 4096, 6144, 2048);
  attn_mfma_kernel<<<512, 256, 0, stream>>>(QKV, Vt_g, H);
  gemm_bt_kernel<0><<<dim3(16, 32), 256, 0, stream>>>(
      H, Wo, (void*)out, nullptr, nullptr, nullptr, 4096, 2048, 2048);
}

// Round 5
// 491.200 us; speedup vs baseline: 1.0086x; 1.0086x over previous
//
#include <hip/hip_runtime.h>

// ---------------------------------------------------------------------------
// Attention_17703855194398: AdaRMSNorm -> QKV -> per-head RMS+RoPE -> SDPA -> out
// B=2, L=2048, D=2048, NH=32, HD=64, DC=2048
// R5: revert rope fusion (R4 regression); keep packed V stores + attn
//     1-barrier pipeline; attn K/V staging via global_load_lds with XOR
//     chunk swizzle (conflict-free reads, no ds_write staging).
// ---------------------------------------------------------------------------

typedef __bf16 bf16x8 __attribute__((ext_vector_type(8)));
typedef float  f32x4  __attribute__((ext_vector_type(4)));
typedef float  f32x16 __attribute__((ext_vector_type(16)));

#define EPS_F32 1.1920929e-07f
// q prescale: (1/sqrt(64)) * log2(e)  -> scores land in exp2 domain
#define QSCALE 0.18033688011112042f

#if defined(__has_builtin)
#  if __has_builtin(__builtin_amdgcn_exp2f)
#    define EXP2F(x) __builtin_amdgcn_exp2f(x)
#  else
#    define EXP2F(x) __expf((x) * 0.6931471805599453f)
#  endif
#  if __has_builtin(__builtin_amdgcn_rcpf)
#    define RCPF(x) __builtin_amdgcn_rcpf(x)
#  else
#    define RCPF(x) (1.0f / (x))
#  endif
#else
#  define EXP2F(x) __expf((x) * 0.6931471805599453f)
#  define RCPF(x) (1.0f / (x))
#endif

__device__ __forceinline__ float bf2f(unsigned int u16) {
  union { unsigned int i; float f; } v; v.i = (u16 & 0xffffu) << 16; return v.f;
}
__device__ __forceinline__ unsigned short f2bf(float f) {
  union { float f; unsigned int i; } v; v.f = f;
  unsigned int r = v.i + 0x7fffu + ((v.i >> 16) & 1u);  // RNE
  return (unsigned short)(r >> 16);
}
// round-to-nearest (ties away) bf16 bits, cheap
__device__ __forceinline__ unsigned int f2bf_rn_u(float f) {
  union { float f; unsigned int i; } v; v.f = f;
  return v.i + 0x8000u;   // caller takes >>16 or &0xffff0000
}

// async global->LDS, 16B per lane (LDS dest = wave-uniform base + lane*16;
// global side is per-lane address)
__device__ __forceinline__ void gload16(const void* g, void* l) {
  __builtin_amdgcn_global_load_lds(
      (const __attribute__((address_space(1))) unsigned int*)(unsigned long long)g,
      (__attribute__((address_space(3))) unsigned int*)(unsigned int)(unsigned long long)l,
      16, 0, 0);
}

// ---------------------------------------------------------------------------
// 1) ada GEMM: ss[b,j] = sum_k cond[b,k] * w_ada[j,k]
// ---------------------------------------------------------------------------
__global__ __launch_bounds__(256) void ada_gemm_kernel(
    const float* __restrict__ cond, const float* __restrict__ w_ada,
    float* __restrict__ ss)
{
  const int lane = threadIdx.x & 63;
  const int gw = blockIdx.x * 4 + (threadIdx.x >> 6);
  const int b = gw >> 12;
  const int j = gw & 4095;
  const float4* wr = (const float4*)(w_ada + j * 2048);
  const float4* cr = (const float4*)(cond + b * 2048);
  float acc = 0.f;
  #pragma unroll
  for (int k4 = 0; k4 < 8; ++k4) {
    float4 w = wr[lane + k4 * 64];
    float4 c = cr[lane + k4 * 64];
    acc += w.x * c.x + w.y * c.y + w.z * c.z + w.w * c.w;
  }
  #pragma unroll
  for (int off = 1; off < 64; off <<= 1) acc += __shfl_xor(acc, off);
  if (lane == 0) ss[b * 4096 + j] = acc;
}

// ---------------------------------------------------------------------------
// 2) AdaRMSNorm: h = rms_norm(x)*(1+scale) + shift, write bf16
// ---------------------------------------------------------------------------
__global__ __launch_bounds__(256) void ada_rms_kernel(
    const float* __restrict__ x, const float* __restrict__ ss,
    unsigned short* __restrict__ H)
{
  const int row = blockIdx.x;
  const int b = row >> 11;
  const int tid = threadIdx.x;
  const int lane = tid & 63, wave = tid >> 6;
  const float* xr = x + (size_t)row * 2048;
  float4 v0 = ((const float4*)xr)[tid * 2];
  float4 v1 = ((const float4*)xr)[tid * 2 + 1];
  float ssq = v0.x*v0.x + v0.y*v0.y + v0.z*v0.z + v0.w*v0.w
            + v1.x*v1.x + v1.y*v1.y + v1.z*v1.z + v1.w*v1.w;
  #pragma unroll
  for (int off = 1; off < 64; off <<= 1) ssq += __shfl_xor(ssq, off);
  __shared__ float red[4];
  if (lane == 0) red[wave] = ssq;
  __syncthreads();
  const float tot = red[0] + red[1] + red[2] + red[3];
  const float r = rsqrtf(tot * (1.f / 2048.f) + EPS_F32);
  const int c0 = tid * 8;
  const float* sh = ss + b * 4096;
  float xv[8] = {v0.x, v0.y, v0.z, v0.w, v1.x, v1.y, v1.z, v1.w};
  unsigned int pk[4];
  #pragma unroll
  for (int p = 0; p < 4; ++p) {
    const int c = c0 + p * 2;
    float h0 = xv[p*2+0] * r * (1.f + sh[2048 + c])     + sh[c];
    float h1 = xv[p*2+1] * r * (1.f + sh[2048 + c + 1]) + sh[c + 1];
    pk[p] = (unsigned int)f2bf(h0) | ((unsigned int)f2bf(h1) << 16);
  }
  *(uint4*)&H[(size_t)row * 2048 + c0] = make_uint4(pk[0], pk[1], pk[2], pk[3]);
}

// ---------------------------------------------------------------------------
// 3) fp32 -> bf16 weight cast, both weights in one launch.
// ---------------------------------------------------------------------------
__global__ __launch_bounds__(256) void cast2_kernel(
    const float* __restrict__ a,   // w_qkv, 3145728 float4
    const float* __restrict__ b,   // w_out, 1048576 float4
    unsigned short* __restrict__ dst)
{
  const int i = blockIdx.x * 256 + threadIdx.x;   // 0..4194303
  float4 v = (i < 3145728) ? ((const float4*)a)[i]
                           : ((const float4*)b)[i - 3145728];
  unsigned int p0 = (unsigned int)f2bf(v.x) | ((unsigned int)f2bf(v.y) << 16);
  unsigned int p1 = (unsigned int)f2bf(v.z) | ((unsigned int)f2bf(v.w) << 16);
  *(uint2*)&dst[(size_t)i * 4] = make_uint2(p0, p1);
}

// ---------------------------------------------------------------------------
// 4) bf16 MFMA GEMM, C[M,N] = A[M,K] @ Bw[N,K]^T (m97 structure).
//    MODE 0: f32 C.  MODE 2: bf16 C for q/k; cols >= 4096 (V third) go to
//    vt[bh][d][k-perm] with 4 perm-contiguous i-values packed per dwordx2.
// ---------------------------------------------------------------------------
template <int MODE>
__global__ __launch_bounds__(256) void gemm_bt_kernel(
    const unsigned short* __restrict__ A,   // [M,K] bf16
    const unsigned short* __restrict__ Bw,  // [N,K] bf16
    void* __restrict__ Cv,                  // [M,N] bf16 or f32
    unsigned short* __restrict__ vt,        // MODE 2 only
    int M, int N, int K)
{
  __shared__ unsigned short As[128 * 32];
  __shared__ unsigned short Bs[128 * 32];
  const int tid  = threadIdx.x;
  const int lane = tid & 63;
  const int wave = tid >> 6;
  const int wm = (wave >> 1) * 64;
  const int wn = (wave & 1) * 64;
  const int bm = blockIdx.y * 128;
  const int bn = blockIdx.x * 128;

  f32x4 acc[4][4] = {};

  const int sm = tid >> 2;
  const int sk = (tid & 3) * 8;
  const unsigned short* Ap  = A  + (size_t)(bm + sm) * K + sk;
  const unsigned short* Ap2 = Ap + (size_t)64 * K;
  const unsigned short* Bp  = Bw + (size_t)(bn + sm) * K + sk;
  const unsigned short* Bp2 = Bp + (size_t)64 * K;
  unsigned short* lA  = &As[tid * 8];
  unsigned short* lA2 = &As[tid * 8 + 2048];
  unsigned short* lB  = &Bs[tid * 8];
  unsigned short* lB2 = &Bs[tid * 8 + 2048];

  const int fr = lane & 15;
  const int fk = (lane >> 4) * 8;

  for (int k0 = 0; k0 < K; k0 += 32) {
    __syncthreads();
    gload16(Ap  + k0, lA);
    gload16(Ap2 + k0, lA2);
    gload16(Bp  + k0, lB);
    gload16(Bp2 + k0, lB2);
    __syncthreads();

    bf16x8 af[4], bfr[4];
    #pragma unroll
    for (int i = 0; i < 4; ++i)
      af[i] = *(const bf16x8*)&As[(wm + i * 16 + fr) * 32 + fk];
    #pragma unroll
    for (int j = 0; j < 4; ++j)
      bfr[j] = *(const bf16x8*)&Bs[(wn + j * 16 + fr) * 32 + fk];
    #pragma unroll
    for (int i = 0; i < 4; ++i)
      #pragma unroll
      for (int j = 0; j < 4; ++j)
        acc[i][j] = __builtin_amdgcn_mfma_f32_16x16x32_bf16(af[i], bfr[j], acc[i][j], 0, 0, 0);
  }

  const int quad = lane >> 4;
  const int cc   = lane & 15;
  const int cr   = quad * 4;

  if (MODE == 2 && bn >= 4096) {
    // V third: Vt[((b*32+head)*64+dim)][2048 k-perm]. For fixed (lane,j,r) the
    // 4 i-values are contiguous in perm order -> one dwordx2 store.
    const int b2 = bm >> 11;
    const int lb = (bm & 2047) + wm;       // perm chunk base (wm in {0,64})
    #pragma unroll
    for (int j = 0; j < 4; ++j) {
      const int dg = bn + wn + j * 16 + cc - 4096;
      unsigned short* vrow = vt + ((size_t)((b2 * 32 + (dg >> 6)) * 64) + (dg & 63)) * 2048;
      #pragma unroll
      for (int r = 0; r < 4; ++r) {
        unsigned int u0 = (unsigned int)f2bf(acc[0][j][r]) | ((unsigned int)f2bf(acc[1][j][r]) << 16);
        unsigned int u1 = (unsigned int)f2bf(acc[2][j][r]) | ((unsigned int)f2bf(acc[3][j][r]) << 16);
        *(uint2*)&vrow[lb + (cr + r) * 4] = make_uint2(u0, u1);
      }
    }
  } else if (MODE == 2) {
    unsigned short* C = (unsigned short*)Cv;
    #pragma unroll
    for (int i = 0; i < 4; ++i)
      #pragma unroll
      for (int j = 0; j < 4; ++j)
        #pragma unroll
        for (int r = 0; r < 4; ++r)
          C[(size_t)(bm + wm + i * 16 + cr + r) * N + bn + wn + j * 16 + cc] =
              f2bf(acc[i][j][r]);
  } else {
    float* C = (float*)Cv;
    #pragma unroll
    for (int i = 0; i < 4; ++i)
      #pragma unroll
      for (int j = 0; j < 4; ++j)
        #pragma unroll
        for (int r = 0; r < 4; ++r)
          C[(size_t)(bm + wm + i * 16 + cr + r) * N + bn + wn + j * 16 + cc] = acc[i][j][r];
  }
}

// ---------------------------------------------------------------------------
// 5) per-head RMSNorm(qk_w) + RoPE on q,k in place; q scaled by QSCALE.
// ---------------------------------------------------------------------------
__global__ __launch_bounds__(256) void qk_rope_kernel(
    unsigned short* __restrict__ QKV, const float* __restrict__ rope,
    const float* __restrict__ qk_w)
{
  const int lane = threadIdx.x & 63;
  const int gid = blockIdx.x * 4 + (threadIdx.x >> 6);
  const int l = gid & 2047;
  const int h = (gid >> 11) & 31;
  const int b = gid >> 16;
  const int base = (b * 2048 + l) * 6144 + h * 64 + lane;
  const float r0 = rope[l * 64 + lane];
  const float r1 = rope[131072 + l * 64 + lane];
  const float w  = qk_w[lane];
  #pragma unroll
  for (int t = 0; t < 2; ++t) {        // t=0: q, t=1: k
    const int idx = base + 2048 * t;
    const float v = bf2f(QKV[idx]);
    float sq = v * v;
    #pragma unroll
    for (int off = 1; off < 64; off <<= 1) sq += __shfl_xor(sq, off);
    const float vn = v * rsqrtf(sq * (1.f / 64.f) + EPS_F32) * w;
    const float vp = __shfl_xor(vn, 1);
    const float vh = (lane & 1) ? vp : -vp;
    const float scale = (t == 0) ? QSCALE : 1.0f;
    QKV[idx] = f2bf((vn * r0 + vh * r1) * scale);
  }
}

// ---------------------------------------------------------------------------
// 6) MFMA flash attention (no-max softmax). 64q/wave, 256q/block, k-tile 64.
//    K/V staged via global_load_lds into an XOR-chunk-swizzled layout
//    (phys_chunk = logical_chunk ^ (row&7), 16B chunks, no padding):
//    conflict-free fragment reads, zero ds_write staging instructions.
//    LDS double-buffer, ONE barrier per kt; prefetch issued at loop top had
//    the whole compute phase to land before the barrier's vmcnt drain.
// ---------------------------------------------------------------------------
#define KVSZ (64 * 64)   // shorts per K or V tile (swizzled, unpadded)
__global__ __launch_bounds__(256, 2) void attn_mfma_kernel(
    const unsigned short* __restrict__ QKV,  // [4096][6144] (q,k roped)
    const unsigned short* __restrict__ Vt,   // [64 bh][64 d][2048 k-perm]
    unsigned short* __restrict__ O)          // [4096][2048]
{
  __shared__ unsigned short Kb[2 * KVSZ];
  __shared__ unsigned short Vb[2 * KVSZ];
  __shared__ unsigned short Ps[4 * 64 * 68];
  const int tid  = threadIdx.x;
  const int lane = tid & 63;
  const int wave = tid >> 6;
  const int blk = blockIdx.x;              // 0..511
  const int bh = blk & 63;                 // XCD-affine
  const int qt = blk >> 6;                 // 0..7
  const int b = bh >> 5, h = bh & 31;
  const int rowbase = b << 11;
  const int qbase = qt * 256 + wave * 64;

  const int m16  = lane & 15;
  const int quad = lane >> 4;
  const int m32  = lane & 31;
  const int hl   = lane >> 5;

  // Q fragments (QSCALE folded in by qk_rope)
  bf16x8 qf[4][2];
  #pragma unroll
  for (int qi = 0; qi < 4; ++qi)
    #pragma unroll
    for (int ch = 0; ch < 2; ++ch)
      qf[qi][ch] = *(const bf16x8*)&QKV[(size_t)(rowbase + qbase + qi * 16 + m16) * 6144
                                        + h * 64 + ch * 32 + quad * 8];

  // --- staging map (per wave: rows wave*16 + c*8 + (lane>>3), c in {0,1}) ---
  const int srow0 = wave * 16 + (lane >> 3);         // c=0 row; c=1 adds 8
  const int sch   = lane & 7;                        // physical chunk slot
  const int kc0 = (sch ^ (srow0 & 7)) * 8;           // logical chunk (shorts), c=0
  const int kc1 = (sch ^ ((srow0 + 8) & 7)) * 8;     // c=1
  // K: row r of tile kt lives at QKV[(rowbase + kt*64 + r)*6144 + 2048 + h*64]
  const unsigned short* Kg0 = QKV + (size_t)(rowbase + srow0) * 6144 + 2048 + h * 64 + kc0;
  const unsigned short* Kg1 = QKV + (size_t)(rowbase + srow0 + 8) * 6144 + 2048 + h * 64 + kc1;
  // V: row d lives at Vt[(bh*64 + d)*2048 + kt*64]
  const unsigned short* Vg0 = Vt + (size_t)(bh * 64 + srow0) * 2048 + kc0;
  const unsigned short* Vg1 = Vt + (size_t)(bh * 64 + srow0 + 8) * 2048 + kc1;
  // LDS dest (per-lane = wave-uniform + lane*16B)
  unsigned short* lK0[2] = { &Kb[(wave * 16) * 64 + (lane & 7) * 8 + ((lane >> 3) & 1) * 512],
                             nullptr };
  // simpler: compute flat per-lane dest = bufbase + (wave*16 + c*8)*64 + (lane)*8
  // (row l>>3, slot l&7  ->  offset (l>>3)*64 + (l&7)*8 = l*8)
  (void)lK0;

  f32x16 accO[2][2] = {};
  float part[4][4] = {};
  unsigned short* Pw = &Ps[(wave * 64) * 68];

  const int ldsW = wave * 16 * 64 + lane * 8;        // c=0 per-lane dest offset

  // stage kt=0 into buffer 0
  gload16(Kg0, &Kb[ldsW]);
  gload16(Kg1, &Kb[ldsW + 512]);
  gload16(Vg0, &Vb[ldsW]);
  gload16(Vg1, &Vb[ldsW + 512]);
  __syncthreads();

  const int x7 = m16 & 7;                 // row&7 for kf reads
  const int kq0 = (quad ^ x7) * 8;        // kf0 swizzled col
  const int kq1 = ((quad ^ x7) ^ 4) * 8;  // kf1 (logical chunk quad+4)
  const int y7 = m32 & 7;                 // row&7 for vb reads

  for (int kt = 0; kt < 32; ++kt) {
    const int cur = kt & 1;
    // prefetch next tile into other buffer (fire-and-forget DMA)
    if (kt < 31) {
      const int nb = (1 - cur) * KVSZ;
      const size_t ko = (size_t)(kt + 1) * 64 * 6144;
      const int    vo = (kt + 1) * 64;
      gload16(Kg0 + ko, &Kb[nb + ldsW]);
      gload16(Kg1 + ko, &Kb[nb + ldsW + 512]);
      gload16(Vg0 + vo, &Vb[nb + ldsW]);
      gload16(Vg1 + vo, &Vb[nb + ldsW + 512]);
    }
    const unsigned short* Ksc = &Kb[cur * KVSZ];
    const unsigned short* Vsc = &Vb[cur * KVSZ];

    // S (16x16x32) -> exp2 -> pack P (key perm p = c*4 + kj)
    unsigned int pk[4][4][2];
    #pragma unroll
    for (int kj = 0; kj < 4; ++kj) {
      bf16x8 kf0 = *(const bf16x8*)&Ksc[(kj * 16 + m16) * 64 + kq0];
      bf16x8 kf1 = *(const bf16x8*)&Ksc[(kj * 16 + m16) * 64 + kq1];
      #pragma unroll
      for (int qi = 0; qi < 4; ++qi) {
        f32x4 acc = {};
        acc = __builtin_amdgcn_mfma_f32_16x16x32_bf16(qf[qi][0], kf0, acc, 0, 0, 0);
        acc = __builtin_amdgcn_mfma_f32_16x16x32_bf16(qf[qi][1], kf1, acc, 0, 0, 0);
        #pragma unroll
        for (int r = 0; r < 4; ++r) {
          float p = EXP2F(acc[r]);
          part[qi][r] += p;
          unsigned int pb = f2bf_rn_u(p);
          if (kj == 0)      pk[qi][r][0]  = pb >> 16;
          else if (kj == 1) pk[qi][r][0] |= pb & 0xffff0000u;
          else if (kj == 2) pk[qi][r][1]  = pb >> 16;
          else              pk[qi][r][1] |= pb & 0xffff0000u;
        }
      }
    }
    #pragma unroll
    for (int qi = 0; qi < 4; ++qi)
      #pragma unroll
      for (int r = 0; r < 4; ++r)
        *(uint2*)&Pw[(qi * 16 + quad * 4 + r) * 68 + m16 * 4] =
            make_uint2(pk[qi][r][0], pk[qi][r][1]);
    // wave-private P region: RAW covered by lgkmcnt, no barrier

    // PV (32x32x16): accO[qs][dt]
    #pragma unroll
    for (int ch = 0; ch < 4; ++ch) {
      const int vc = ((2 * ch + hl) ^ y7) * 8;   // swizzled V col
      bf16x8 pa0 = *(const bf16x8*)&Pw[m32 * 68 + ch * 16 + hl * 8];
      bf16x8 pa1 = *(const bf16x8*)&Pw[(32 + m32) * 68 + ch * 16 + hl * 8];
      bf16x8 vb0 = *(const bf16x8*)&Vsc[m32 * 64 + vc];
      bf16x8 vb1 = *(const bf16x8*)&Vsc[(32 + m32) * 64 + vc];
      accO[0][0] = __builtin_amdgcn_mfma_f32_32x32x16_bf16(pa0, vb0, accO[0][0], 0, 0, 0);
      accO[0][1] = __builtin_amdgcn_mfma_f32_32x32x16_bf16(pa0, vb1, accO[0][1], 0, 0, 0);
      accO[1][0] = __builtin_amdgcn_mfma_f32_32x32x16_bf16(pa1, vb0, accO[1][0], 0, 0, 0);
      accO[1][1] = __builtin_amdgcn_mfma_f32_32x32x16_bf16(pa1, vb1, accO[1][1], 0, 0, 0);
    }

    __syncthreads();   // waits lgkm (LDS reads done) + vm (prefetch landed)
  }

  // reduce row sums over the 16 n-lanes
  #pragma unroll
  for (int qi = 0; qi < 4; ++qi)
    #pragma unroll
    for (int r = 0; r < 4; ++r)
      #pragma unroll
      for (int off = 1; off < 16; off <<= 1)
        part[qi][r] += __shfl_xor(part[qi][r], off);

  // epilogue: per 32-row q-subtile, gather row sum, divide, store
  #pragma unroll
  for (int qs = 0; qs < 2; ++qs) {
    #pragma unroll
    for (int reg = 0; reg < 16; ++reg) {
      const int r = reg & 3;
      const int s = reg >> 2;
      const int qsrc = ((2 * s + hl) & 3) * 16 + m16;
      const float rs = __shfl(part[qs * 2 + (reg >> 3)][r], qsrc);
      const float inv = RCPF(rs);
      const int rho = r + 8 * s + 4 * hl;
      const size_t base = (size_t)(rowbase + qbase + qs * 32 + rho) * 2048 + h * 64;
      O[base + m32]      = f2bf(accO[qs][0][reg] * inv);
      O[base + 32 + m32] = f2bf(accO[qs][1][reg] * inv);
    }
  }
}

// ---------------------------------------------------------------------------
// launch
// ---------------------------------------------------------------------------
extern "C" void kernel_launch(void* const* d_in, const int* in_sizes, int n_in,
                              void* d_out, int out_size, void* d_ws, size_t ws_size,
                              hipStream_t stream) {
  (void)in_sizes; (void)n_in; (void)out_size; (void)ws_size;
  const float* x     = (const float*)d_in[0];
  const float* cond  = (const float*)d_in[1];
  const float* rope  = (const float*)d_in[2];
  const float* w_ada = (const float*)d_in[3];
  const float* w_qkv = (const float*)d_in[4];
  const float* w_out = (const float*)d_in[5];
  const float* qk_w  = (const float*)d_in[6];
  float* out = (float*)d_out;

  char* ws = (char*)d_ws;
  float*          ss   = (float*)ws;                       // 32 KB
  unsigned short* H    = (unsigned short*)(ws + 32768);    // 16 MB, reused as O
  unsigned short* Wq   = H + 8388608;                      // 24 MB
  unsigned short* Wo   = Wq + 12582912;                    // 8 MB (contiguous after Wq)
  unsigned short* QKV  = Wo + 4194304;                     // 48 MB (q,k used)
  unsigned short* Vt_g = QKV + 25165824;                   // 16 MB

  ada_gemm_kernel<<<2048, 256, 0, stream>>>(cond, w_ada, ss);
  ada_rms_kernel<<<4096, 256, 0, stream>>>(x, ss, H);
  cast2_kernel<<<16384, 256, 0, stream>>>(w_qkv, w_out, Wq);
  // qkv = H @ w_qkv^T ; q,k -> QKV, v -> Vt_g (transposed + k-permuted)
  gemm_bt_kernel<2><<<dim3(48, 32), 256, 0, stream>>>(H, Wq, (void*)QKV, Vt_g, 4096, 6144, 2048);
  qk_rope_kernel<<<32768, 256, 0, stream>>>(QKV, rope, qk_w);
  attn_mfma_kernel<<<512, 256, 0, stream>>>(QKV, Vt_g, H);
  gemm_bt_kernel<0><<<dim3(16, 32), 256, 0, stream>>>(H, Wo, (void*)out, nullptr, 4096, 2048, 2048);
}